// Round 1
// baseline (357.021 us; speedup 1.0000x reference)
//
#include <hip/hip_runtime.h>

typedef __bf16 bf16_t;
typedef __bf16 bf16x8 __attribute__((ext_vector_type(8)));
typedef __bf16 bf16x4 __attribute__((ext_vector_type(4)));
typedef float  f32x4  __attribute__((ext_vector_type(4)));

// ---------------------------------------------------------------------------
// Workspace layout (floats unless noted):
//   A  : [4096][256] f32   (xf @ W1[0:26])                       4 MB
//   C  : [4096][256] f32   (xf @ W1[26:52] + qst @ W1[52:180] + b1)  4 MB
//   Wt : 3 x [256][256] bf16, g2/g3/g4 weights transposed [out][in]  384 KB
//   xg : [64][256] f32     (pair-summed g output)                64 KB
// ---------------------------------------------------------------------------

// swizzled LDS column index: 16B-block XOR on row low bits.
__device__ __forceinline__ int swz(int row, int col) {
  return (((col >> 3) ^ (row & 7)) << 3) | (col & 7);
}

// ---------------- prep: A, C, weight transpose+cast, zero xg ----------------
__global__ __launch_bounds__(256) void rn_prep_kernel(
    const float* __restrict__ x, const float* __restrict__ qst,
    const float* __restrict__ g1w, const float* __restrict__ g1b,
    const float* __restrict__ g2w, const float* __restrict__ g3w,
    const float* __restrict__ g4w,
    float* __restrict__ A, float* __restrict__ C,
    bf16_t* __restrict__ Wt, float* __restrict__ xg)
{
  __shared__ float T[64][65];   // transpose tile (only used by that branch)
  int blk = blockIdx.x;
  int n   = threadIdx.x;  // 0..255
  if (blk < 256) {
    // block = (b, jg): rows jg*16 .. jg*16+15 of batch b; thread = output col n
    int b  = blk >> 2;
    int jg = (blk & 3) * 16;
    float accQ = g1b[n];
    const float* qb = qst + b * 128;
    #pragma unroll 8
    for (int qi = 0; qi < 128; ++qi)
      accQ += qb[qi] * g1w[(52 + qi) * 256 + n];

    float w24 = g1w[24 * 256 + n], w25 = g1w[25 * 256 + n];
    float w50 = g1w[50 * 256 + n], w51 = g1w[51 * 256 + n];
    float accA[16], accC[16];
    #pragma unroll
    for (int t = 0; t < 16; ++t) {
      int j = jg + t;
      // faithful to (a/d - d/2)/(d/2.0) float arithmetic, d=8 (exact pow2 ops)
      float cx = ((float)j * 0.125f - 4.0f) * 0.25f;
      float cy = ((float)(j & 7) - 4.0f) * 0.25f;
      accA[t] = cx * w24 + cy * w25;
      accC[t] = accQ + cx * w50 + cy * w51;
    }
    for (int c = 0; c < 24; ++c) {
      float wa = g1w[c * 256 + n];
      float wc = g1w[(26 + c) * 256 + n];
      const float* xc = x + (b * 24 + c) * 64 + jg;
      #pragma unroll
      for (int t = 0; t < 16; ++t) {
        float xv = xc[t];   // uniform per thread -> scalar load
        accA[t] += xv * wa;
        accC[t] += xv * wc;
      }
    }
    #pragma unroll
    for (int t = 0; t < 16; ++t) {
      A[(b * 64 + jg + t) * 256 + n] = accA[t];
      C[(b * 64 + jg + t) * 256 + n] = accC[t];
    }
  } else if (blk < 256 + 48) {
    // LDS-tiled transpose: g2/g3/g4 [in(k)][out(no)] f32 -> bf16 [no][k]
    int t   = blk - 256;
    int mat = t >> 4;                 // 0..2
    int tl  = t & 15;                 // 4x4 tiles of 64x64
    int kt  = (tl & 3) * 64;
    int nt_ = (tl >> 2) * 64;
    const float* W = (mat == 0) ? g2w : (mat == 1 ? g3w : g4w);
    int lane = n & 63, w = n >> 6;
    #pragma unroll
    for (int it = 0; it < 16; ++it) {
      int kl = w * 16 + it;
      T[kl][lane] = W[(kt + kl) * 256 + nt_ + lane];   // coalesced 256B/wave
    }
    __syncthreads();
    #pragma unroll
    for (int it = 0; it < 16; ++it) {
      int nl = w * 16 + it;
      Wt[mat * 65536 + (nt_ + nl) * 256 + kt + lane] = (bf16_t)T[lane][nl];
    }
  } else {
    int idx = (blk - (256 + 48)) * 256 + n;  // 64 blocks -> 16384
    xg[idx] = 0.f;
  }
}

// ---------------- main fused g-MLP (layers 2..4) + pair sum ----------------
// one block per (b, i): M = 64 rows (1 i-value x 64 j), N = K = 256.
// Occupancy restructure vs previous version: per-wave tile 64x64 ->
// acc[4][4] = 64 AGPRs, total ~120 regs/wave -> 4 waves/SIMD (was 2).
// LDS = 32 KB -> 4 blocks/CU. TLP now hides the per-ks load latency that
// previously left the matrix pipe idle ~70% (MfmaUtil 27%).
// Operand-swapped MFMA unchanged: A-operand = W (n-index -> D rows),
// B-operand = h (m-index -> D cols). D: col=lane&15=m-within,
// row=quad*4+rg=n-within -> epilogue writes are row-contiguous bf16x4.
__global__ __launch_bounds__(256, 4) void rn_main_kernel(
    const float* __restrict__ A, const float* __restrict__ C,
    const bf16_t* __restrict__ Wt,
    const float* __restrict__ g2b, const float* __restrict__ g3b,
    const float* __restrict__ g4b,
    float* __restrict__ xg)
{
  __shared__ bf16_t hbuf[64][256];   // 32 KB, XOR-swizzled cols

  int tid  = threadIdx.x;
  int bx0  = blockIdx.x;
  // bijective XCD swizzle (4096 % 8 == 0): 512 consecutive work-units per
  // XCD -> the 64 blocks sharing a batch b stay on one XCD's L2 (A locality)
  int bx   = (bx0 & 7) * 512 + (bx0 >> 3);
  int b    = bx >> 6;          // batch
  int i    = bx & 63;          // i-object
  int lane = tid & 63;
  int wave = tid >> 6;
  int n0   = wave * 64;
  int r    = lane & 15;        // 16-dim index within MFMA tile
  int q    = lane >> 4;        // quad: k-chunk selector / D-row group

  // ---- build h1 rows: row j = relu(A[b,j,:] + C[b,i,:]) ----
  {
    const float* Ab = A + (size_t)b * 64 * 256;
    const float* Cr = C + ((size_t)b * 64 + i) * 256;
    int n = lane * 4;
    const float4 c4 = *(const float4*)(Cr + n);   // loaded once, reused x16
    #pragma unroll
    for (int it = 0; it < 16; ++it) {
      int j = it * 4 + wave;
      const float4 a4 = *(const float4*)(Ab + j * 256 + n);
      bf16x4 v;
      v[0] = (bf16_t)fmaxf(a4.x + c4.x, 0.f);
      v[1] = (bf16_t)fmaxf(a4.y + c4.y, 0.f);
      v[2] = (bf16_t)fmaxf(a4.z + c4.z, 0.f);
      v[3] = (bf16_t)fmaxf(a4.w + c4.w, 0.f);
      *(bf16x4*)&hbuf[j][swz(j, n)] = v;
    }
  }

  const float* biases[3] = {g2b, g3b, g4b};

  for (int L = 0; L < 3; ++L) {
    __syncthreads();     // h ready for reads
    const bf16_t* W = Wt + L * 65536;
    const float* bias = biases[L];

    f32x4 acc[4][4];     // [nt][mt] -- 64 AGPRs
    #pragma unroll
    for (int nt = 0; nt < 4; ++nt)
      #pragma unroll
      for (int mt = 0; mt < 4; ++mt)
        #pragma unroll
        for (int e = 0; e < 4; ++e) acc[nt][mt][e] = 0.f;

    #pragma unroll
    for (int ks = 0; ks < 8; ++ks) {
      int k0 = ks * 32 + q * 8;    // this lane's 8-element k-run
      bf16x8 wf[4], hf[4];
      #pragma unroll
      for (int nt = 0; nt < 4; ++nt)
        wf[nt] = *(const bf16x8*)&W[(n0 + nt * 16 + r) * 256 + k0];
      #pragma unroll
      for (int mt = 0; mt < 4; ++mt) {
        int row = mt * 16 + r;
        hf[mt] = *(const bf16x8*)&hbuf[row][swz(row, k0)];
      }
      #pragma unroll
      for (int nt = 0; nt < 4; ++nt)
        #pragma unroll
        for (int mt = 0; mt < 4; ++mt)
          acc[nt][mt] = __builtin_amdgcn_mfma_f32_16x16x32_bf16(
              wf[nt], hf[mt], acc[nt][mt], 0, 0, 0);
    }

    float4 bv[4];        // biases for n = n0 + nt*16 + q*4 + rg
    #pragma unroll
    for (int nt = 0; nt < 4; ++nt)
      bv[nt] = *(const float4*)&bias[n0 + nt * 16 + q * 4];

    if (L < 2) {
      __syncthreads();   // all reads of hbuf done -> safe to overwrite
      #pragma unroll
      for (int nt = 0; nt < 4; ++nt) {
        int col = n0 + nt * 16 + q * 4;
        #pragma unroll
        for (int mt = 0; mt < 4; ++mt) {
          int row = mt * 16 + r;
          bf16x4 v;
          v[0] = (bf16_t)fmaxf(acc[nt][mt][0] + bv[nt].x, 0.f);
          v[1] = (bf16_t)fmaxf(acc[nt][mt][1] + bv[nt].y, 0.f);
          v[2] = (bf16_t)fmaxf(acc[nt][mt][2] + bv[nt].z, 0.f);
          v[3] = (bf16_t)fmaxf(acc[nt][mt][3] + bv[nt].w, 0.f);
          *(bf16x4*)&hbuf[row][swz(row, col)] = v;
        }
      }
    } else {
      // last layer: bias+relu fp32, sum over the 64 m-rows, atomic to xg.
      // m = mt*16 + r: sum over mt in-register, then over the 16 r-lanes.
      #pragma unroll
      for (int nt = 0; nt < 4; ++nt) {
        float p0 = 0.f, p1 = 0.f, p2 = 0.f, p3 = 0.f;
        #pragma unroll
        for (int mt = 0; mt < 4; ++mt) {
          p0 += fmaxf(acc[nt][mt][0] + bv[nt].x, 0.f);
          p1 += fmaxf(acc[nt][mt][1] + bv[nt].y, 0.f);
          p2 += fmaxf(acc[nt][mt][2] + bv[nt].z, 0.f);
          p3 += fmaxf(acc[nt][mt][3] + bv[nt].w, 0.f);
        }
        #pragma unroll
        for (int d = 1; d < 16; d <<= 1) {
          p0 += __shfl_xor(p0, d, 64);
          p1 += __shfl_xor(p1, d, 64);
          p2 += __shfl_xor(p2, d, 64);
          p3 += __shfl_xor(p3, d, 64);
        }
        if (r == 0) {
          int n = b * 256 + n0 + nt * 16 + q * 4;
          atomicAdd(&xg[n + 0], p0);
          atomicAdd(&xg[n + 1], p1);
          atomicAdd(&xg[n + 2], p2);
          atomicAdd(&xg[n + 3], p3);
        }
      }
    }
  }
}

// ---------------- f-MLP + log_softmax (tiny, fp32) ----------------
__global__ __launch_bounds__(256) void rn_f_kernel(
    const float* __restrict__ xg,
    const float* __restrict__ f1w, const float* __restrict__ f1b,
    const float* __restrict__ f2w, const float* __restrict__ f2b,
    const float* __restrict__ f3w, const float* __restrict__ f3b,
    float* __restrict__ out)
{
  __shared__ float xs[256], t1[256], t2[256], lg[28], lse[1];
  int b = blockIdx.x, tid = threadIdx.x;
  xs[tid] = xg[b * 256 + tid];
  __syncthreads();
  float acc = f1b[tid];
  for (int k = 0; k < 256; ++k) acc += xs[k] * f1w[k * 256 + tid];
  t1[tid] = fmaxf(acc, 0.f);
  __syncthreads();
  acc = f2b[tid];
  for (int k = 0; k < 256; ++k) acc += t1[k] * f2w[k * 256 + tid];
  t2[tid] = fmaxf(acc, 0.f);
  __syncthreads();
  if (tid < 28) {
    float a2 = f3b[tid];
    for (int k = 0; k < 256; ++k) a2 += t2[k] * f3w[k * 28 + tid];
    lg[tid] = a2;
  }
  __syncthreads();
  if (tid == 0) {
    float m = lg[0];
    for (int j = 1; j < 28; ++j) m = fmaxf(m, lg[j]);
    float se = 0.f;
    for (int j = 0; j < 28; ++j) se += expf(lg[j] - m);
    lse[0] = m + logf(se);
  }
  __syncthreads();
  if (tid < 28) out[b * 28 + tid] = lg[tid] - lse[0];
}

// ---------------------------------------------------------------------------
extern "C" void kernel_launch(void* const* d_in, const int* in_sizes, int n_in,
                              void* d_out, int out_size, void* d_ws, size_t ws_size,
                              hipStream_t stream) {
  (void)in_sizes; (void)n_in; (void)out_size; (void)ws_size;
  const float* x   = (const float*)d_in[0];
  const float* qst = (const float*)d_in[1];
  const float* g1w = (const float*)d_in[2];
  const float* g1b = (const float*)d_in[3];
  const float* g2w = (const float*)d_in[4];
  const float* g2b = (const float*)d_in[5];
  const float* g3w = (const float*)d_in[6];
  const float* g3b = (const float*)d_in[7];
  const float* g4w = (const float*)d_in[8];
  const float* g4b = (const float*)d_in[9];
  const float* f1w = (const float*)d_in[10];
  const float* f1b = (const float*)d_in[11];
  const float* f2w = (const float*)d_in[12];
  const float* f2b = (const float*)d_in[13];
  const float* f3w = (const float*)d_in[14];
  const float* f3b = (const float*)d_in[15];
  float* out = (float*)d_out;

  float*  A  = (float*)d_ws;
  float*  C  = A + 4096 * 256;
  bf16_t* Wt = (bf16_t*)(C + 4096 * 256);
  float*  xg = (float*)((char*)Wt + 3 * 65536 * sizeof(bf16_t));

  rn_prep_kernel<<<256 + 48 + 64, 256, 0, stream>>>(
      x, qst, g1w, g1b, g2w, g3w, g4w, A, C, Wt, xg);
  rn_main_kernel<<<4096, 256, 0, stream>>>(A, C, Wt, g2b, g3b, g4b, xg);
  rn_f_kernel<<<64, 256, 0, stream>>>(xg, f1w, f1b, f2w, f2b, f3w, f3b, out);
}

// Round 2
// 344.747 us; speedup vs baseline: 1.0356x; 1.0356x over previous
//
#include <hip/hip_runtime.h>

typedef __bf16 bf16_t;
typedef __bf16 bf16x8 __attribute__((ext_vector_type(8)));
typedef __bf16 bf16x4 __attribute__((ext_vector_type(4)));
typedef float  f32x4  __attribute__((ext_vector_type(4)));

// ---------------------------------------------------------------------------
// Workspace layout (floats unless noted):
//   A  : [4096][256] f32   (xf @ W1[0:26])                       4 MB
//   C  : [4096][256] f32   (xf @ W1[26:52] + qst @ W1[52:180] + b1)  4 MB
//   Wt : 3 x [256][256] bf16, g2/g3/g4 weights, MFMA-fragment layout
//        [mat][wave(n>>6)][nt][ks][lane][8]  -> per-(nt,ks) loads are one
//        coalesced 1 KB wave transaction.                        384 KB
//   xg : [64][256] f32     (pair-summed g output)                64 KB
// ---------------------------------------------------------------------------

// swizzled LDS column index: 16B-block XOR on row low bits.
__device__ __forceinline__ int swz(int row, int col) {
  return (((col >> 3) ^ (row & 7)) << 3) | (col & 7);
}

// ---------------- prep: A, C, weight fragment-relayout, zero xg -------------
__global__ __launch_bounds__(256) void rn_prep_kernel(
    const float* __restrict__ x, const float* __restrict__ qst,
    const float* __restrict__ g1w, const float* __restrict__ g1b,
    const float* __restrict__ g2w, const float* __restrict__ g3w,
    const float* __restrict__ g4w,
    float* __restrict__ A, float* __restrict__ C,
    bf16_t* __restrict__ Wt, float* __restrict__ xg)
{
  __shared__ float T[64][65];   // transpose tile (only used by that branch)
  int blk = blockIdx.x;
  int n   = threadIdx.x;  // 0..255
  if (blk < 256) {
    // block = (b, jg): rows jg*16 .. jg*16+15 of batch b; thread = output col n
    int b  = blk >> 2;
    int jg = (blk & 3) * 16;
    float accQ = g1b[n];
    const float* qb = qst + b * 128;
    #pragma unroll 8
    for (int qi = 0; qi < 128; ++qi)
      accQ += qb[qi] * g1w[(52 + qi) * 256 + n];

    float w24 = g1w[24 * 256 + n], w25 = g1w[25 * 256 + n];
    float w50 = g1w[50 * 256 + n], w51 = g1w[51 * 256 + n];
    float accA[16], accC[16];
    #pragma unroll
    for (int t = 0; t < 16; ++t) {
      int j = jg + t;
      // faithful to (a/d - d/2)/(d/2.0) float arithmetic, d=8 (exact pow2 ops)
      float cx = ((float)j * 0.125f - 4.0f) * 0.25f;
      float cy = ((float)(j & 7) - 4.0f) * 0.25f;
      accA[t] = cx * w24 + cy * w25;
      accC[t] = accQ + cx * w50 + cy * w51;
    }
    for (int c = 0; c < 24; ++c) {
      float wa = g1w[c * 256 + n];
      float wc = g1w[(26 + c) * 256 + n];
      const float* xc = x + (b * 24 + c) * 64 + jg;
      #pragma unroll
      for (int t = 0; t < 16; ++t) {
        float xv = xc[t];   // uniform per thread -> scalar load
        accA[t] += xv * wa;
        accC[t] += xv * wc;
      }
    }
    #pragma unroll
    for (int t = 0; t < 16; ++t) {
      A[(b * 64 + jg + t) * 256 + n] = accA[t];
      C[(b * 64 + jg + t) * 256 + n] = accC[t];
    }
  } else if (blk < 256 + 48) {
    // LDS-tiled transpose: g2/g3/g4 [in(k)][out(no)] f32 -> bf16 fragment
    // layout [wv][nt][ks][lane(q*16+r)][e]: element (no,k) goes to
    //   wv=no>>6, nt=(no>>4)&3, r=no&15, ks=k>>5, q=(k>>3)&3, e=k&7
    int t   = blk - 256;
    int mat = t >> 4;                 // 0..2
    int tl  = t & 15;                 // 4x4 tiles of 64x64
    int kt  = (tl & 3) * 64;
    int nt_ = (tl >> 2) * 64;
    const float* W = (mat == 0) ? g2w : (mat == 1 ? g3w : g4w);
    int lane = n & 63, w = n >> 6;
    #pragma unroll
    for (int it = 0; it < 16; ++it) {
      int kl = w * 16 + it;
      T[kl][lane] = W[(kt + kl) * 256 + nt_ + lane];   // coalesced 256B/wave
    }
    __syncthreads();
    #pragma unroll
    for (int it = 0; it < 16; ++it) {
      int nl  = w * 16 + it;
      int no  = nt_ + nl;     // output-neuron index
      int k   = kt + lane;    // input index
      int wv  = no >> 6, rr = no & 15, ntI = (no >> 4) & 3;
      int ksI = k >> 5,  qI = (k >> 3) & 3, e = k & 7;
      int idx = ((((wv * 4 + ntI) * 8 + ksI) * 64) + qI * 16 + rr) * 8 + e;
      Wt[mat * 65536 + idx] = (bf16_t)T[lane][nl];
    }
  } else {
    int idx = (blk - (256 + 48)) * 256 + n;  // 64 blocks -> 16384
    xg[idx] = 0.f;
  }
}

// ---------------- main fused g-MLP (layers 2..4) + pair sum ----------------
// one block per (b, i-pair); TWO sequential i-passes (M=64 each) over two
// 32 KB h-buffers share a register-stationary W slice:
//   per layer, each wave loads its 64-row W slice ONCE into 128 VGPRs
//   (32 coalesced dwordx4 loads), then both i-passes run pure LDS+MFMA.
// This removes the per-ks global W loads that serialized the old kernels
// (MfmaUtil 27% at M=128, 16% at M=64) and halves W L2 traffic.
// LDS 64 KB -> 2 blocks/CU. Regs: wreg 128 + acc 64 + hf 16 + addr ~ 230.
__global__ __launch_bounds__(256, 2) void rn_main_kernel(
    const float* __restrict__ A, const float* __restrict__ C,
    const bf16_t* __restrict__ Wt,
    const float* __restrict__ g2b, const float* __restrict__ g3b,
    const float* __restrict__ g4b,
    float* __restrict__ xg)
{
  __shared__ bf16_t h0[64][256];   // 32 KB, XOR-swizzled cols
  __shared__ bf16_t h1[64][256];   // 32 KB

  int tid  = threadIdx.x;
  int bx0  = blockIdx.x;
  // bijective XCD swizzle (2048 % 8 == 0): 256 consecutive work-units per
  // XCD -> the 32 blocks sharing a batch b stay on one XCD's L2
  int bx   = (bx0 & 7) * 256 + (bx0 >> 3);
  int b    = bx >> 5;          // batch
  int ip   = bx & 31;          // i-pair: i = 2*ip, 2*ip+1
  int lane = tid & 63;
  int wave = tid >> 6;
  int n0   = wave * 64;
  int r    = lane & 15;        // 16-dim index within MFMA tile
  int q    = lane >> 4;        // quad: k-chunk selector / D-row group

  // ---- build h rows: h{0,1}[j] = relu(A[b,j,:] + C[b,2ip+{0,1},:]) ----
  {
    const float* Ab = A + (size_t)b * 64 * 256;
    const float* Cr = C + ((size_t)b * 64 + ip * 2) * 256;
    int nn = lane * 4;
    const float4 c0 = *(const float4*)(Cr + nn);
    const float4 c1 = *(const float4*)(Cr + 256 + nn);
    #pragma unroll
    for (int it = 0; it < 16; ++it) {
      int j = it * 4 + wave;
      const float4 a4 = *(const float4*)(Ab + j * 256 + nn);
      bf16x4 v0, v1;
      v0[0] = (bf16_t)fmaxf(a4.x + c0.x, 0.f);
      v0[1] = (bf16_t)fmaxf(a4.y + c0.y, 0.f);
      v0[2] = (bf16_t)fmaxf(a4.z + c0.z, 0.f);
      v0[3] = (bf16_t)fmaxf(a4.w + c0.w, 0.f);
      v1[0] = (bf16_t)fmaxf(a4.x + c1.x, 0.f);
      v1[1] = (bf16_t)fmaxf(a4.y + c1.y, 0.f);
      v1[2] = (bf16_t)fmaxf(a4.z + c1.z, 0.f);
      v1[3] = (bf16_t)fmaxf(a4.w + c1.w, 0.f);
      *(bf16x4*)&h0[j][swz(j, nn)] = v0;
      *(bf16x4*)&h1[j][swz(j, nn)] = v1;
    }
  }

#define KS_LOOP(HB, ACC)                                                \
  {                                                                     \
    _Pragma("unroll")                                                   \
    for (int ks = 0; ks < 8; ++ks) {                                    \
      int k0 = ks * 32 + q * 8;                                         \
      bf16x8 hf[4];                                                     \
      _Pragma("unroll")                                                 \
      for (int mt = 0; mt < 4; ++mt) {                                  \
        int row = mt * 16 + r;                                          \
        hf[mt] = *(const bf16x8*)&HB[row][swz(row, k0)];                \
      }                                                                 \
      _Pragma("unroll")                                                 \
      for (int nt = 0; nt < 4; ++nt)                                    \
        _Pragma("unroll")                                               \
        for (int mt = 0; mt < 4; ++mt)                                  \
          ACC[nt][mt] = __builtin_amdgcn_mfma_f32_16x16x32_bf16(        \
              wreg[nt][ks], hf[mt], ACC[nt][mt], 0, 0, 0);              \
    }                                                                   \
  }

#define EPILOGUE(HB, ACC)                                               \
  {                                                                     \
    _Pragma("unroll")                                                   \
    for (int nt = 0; nt < 4; ++nt) {                                    \
      float4 bv = *(const float4*)&bias[n0 + nt * 16 + q * 4];          \
      int col = n0 + nt * 16 + q * 4;                                   \
      _Pragma("unroll")                                                 \
      for (int mt = 0; mt < 4; ++mt) {                                  \
        int row = mt * 16 + r;                                          \
        bf16x4 v;                                                       \
        v[0] = (bf16_t)fmaxf(ACC[nt][mt][0] + bv.x, 0.f);               \
        v[1] = (bf16_t)fmaxf(ACC[nt][mt][1] + bv.y, 0.f);               \
        v[2] = (bf16_t)fmaxf(ACC[nt][mt][2] + bv.z, 0.f);               \
        v[3] = (bf16_t)fmaxf(ACC[nt][mt][3] + bv.w, 0.f);               \
        *(bf16x4*)&HB[row][swz(row, col)] = v;                          \
      }                                                                 \
    }                                                                   \
  }

#define REDUCE_ATOMIC(ACC)                                              \
  {                                                                     \
    _Pragma("unroll")                                                   \
    for (int nt = 0; nt < 4; ++nt) {                                    \
      float4 bv = *(const float4*)&bias[n0 + nt * 16 + q * 4];          \
      float p0 = 0.f, p1 = 0.f, p2 = 0.f, p3 = 0.f;                     \
      _Pragma("unroll")                                                 \
      for (int mt = 0; mt < 4; ++mt) {                                  \
        p0 += fmaxf(ACC[nt][mt][0] + bv.x, 0.f);                        \
        p1 += fmaxf(ACC[nt][mt][1] + bv.y, 0.f);                        \
        p2 += fmaxf(ACC[nt][mt][2] + bv.z, 0.f);                        \
        p3 += fmaxf(ACC[nt][mt][3] + bv.w, 0.f);                        \
      }                                                                 \
      _Pragma("unroll")                                                 \
      for (int d = 1; d < 16; d <<= 1) {                                \
        p0 += __shfl_xor(p0, d, 64);                                    \
        p1 += __shfl_xor(p1, d, 64);                                    \
        p2 += __shfl_xor(p2, d, 64);                                    \
        p3 += __shfl_xor(p3, d, 64);                                    \
      }                                                                 \
      if (r == 0) {                                                     \
        int nn = b * 256 + n0 + nt * 16 + q * 4;                        \
        atomicAdd(&xg[nn + 0], p0);                                     \
        atomicAdd(&xg[nn + 1], p1);                                     \
        atomicAdd(&xg[nn + 2], p2);                                     \
        atomicAdd(&xg[nn + 3], p3);                                     \
      }                                                                 \
    }                                                                   \
  }

  #pragma unroll
  for (int L = 0; L < 3; ++L) {
    // register-stationary W slice for this wave: 32 coalesced 1 KB loads
    const bf16_t* Wl = Wt + L * 65536 + wave * 16384;
    bf16x8 wreg[4][8];
    #pragma unroll
    for (int nt = 0; nt < 4; ++nt)
      #pragma unroll
      for (int ks = 0; ks < 8; ++ks)
        wreg[nt][ks] = *(const bf16x8*)&Wl[((nt * 8 + ks) * 64 + lane) * 8];

    const float* bias = (L == 0) ? g2b : (L == 1) ? g3b : g4b;

    if (L == 0) __syncthreads();     // h-build visible

    // ---- i0 pass ----
    {
      f32x4 acc[4][4];
      #pragma unroll
      for (int nt = 0; nt < 4; ++nt)
        #pragma unroll
        for (int mt = 0; mt < 4; ++mt)
          #pragma unroll
          for (int e = 0; e < 4; ++e) acc[nt][mt][e] = 0.f;
      KS_LOOP(h0, acc)
      __syncthreads();               // all h0 reads done (and prev h1 writes)
      if (L < 2) {
        EPILOGUE(h0, acc)
      } else {
        REDUCE_ATOMIC(acc)
      }
    }

    // ---- i1 pass (reuses wreg) ----
    {
      f32x4 acc[4][4];
      #pragma unroll
      for (int nt = 0; nt < 4; ++nt)
        #pragma unroll
        for (int mt = 0; mt < 4; ++mt)
          #pragma unroll
          for (int e = 0; e < 4; ++e) acc[nt][mt][e] = 0.f;
      KS_LOOP(h1, acc)
      if (L < 2) {
        __syncthreads();             // h1 reads + h0 epilogue writes done
        EPILOGUE(h1, acc)
      } else {
        REDUCE_ATOMIC(acc)
      }
    }
  }
#undef KS_LOOP
#undef EPILOGUE
#undef REDUCE_ATOMIC
}

// ---------------- f-MLP + log_softmax (tiny, fp32) ----------------
__global__ __launch_bounds__(256) void rn_f_kernel(
    const float* __restrict__ xg,
    const float* __restrict__ f1w, const float* __restrict__ f1b,
    const float* __restrict__ f2w, const float* __restrict__ f2b,
    const float* __restrict__ f3w, const float* __restrict__ f3b,
    float* __restrict__ out)
{
  __shared__ float xs[256], t1[256], t2[256], lg[28], lse[1];
  int b = blockIdx.x, tid = threadIdx.x;
  xs[tid] = xg[b * 256 + tid];
  __syncthreads();
  float acc = f1b[tid];
  for (int k = 0; k < 256; ++k) acc += xs[k] * f1w[k * 256 + tid];
  t1[tid] = fmaxf(acc, 0.f);
  __syncthreads();
  acc = f2b[tid];
  for (int k = 0; k < 256; ++k) acc += t1[k] * f2w[k * 256 + tid];
  t2[tid] = fmaxf(acc, 0.f);
  __syncthreads();
  if (tid < 28) {
    float a2 = f3b[tid];
    for (int k = 0; k < 256; ++k) a2 += t2[k] * f3w[k * 28 + tid];
    lg[tid] = a2;
  }
  __syncthreads();
  if (tid == 0) {
    float m = lg[0];
    for (int j = 1; j < 28; ++j) m = fmaxf(m, lg[j]);
    float se = 0.f;
    for (int j = 0; j < 28; ++j) se += expf(lg[j] - m);
    lse[0] = m + logf(se);
  }
  __syncthreads();
  if (tid < 28) out[b * 28 + tid] = lg[tid] - lse[0];
}

// ---------------------------------------------------------------------------
extern "C" void kernel_launch(void* const* d_in, const int* in_sizes, int n_in,
                              void* d_out, int out_size, void* d_ws, size_t ws_size,
                              hipStream_t stream) {
  (void)in_sizes; (void)n_in; (void)out_size; (void)ws_size;
  const float* x   = (const float*)d_in[0];
  const float* qst = (const float*)d_in[1];
  const float* g1w = (const float*)d_in[2];
  const float* g1b = (const float*)d_in[3];
  const float* g2w = (const float*)d_in[4];
  const float* g2b = (const float*)d_in[5];
  const float* g3w = (const float*)d_in[6];
  const float* g3b = (const float*)d_in[7];
  const float* g4w = (const float*)d_in[8];
  const float* g4b = (const float*)d_in[9];
  const float* f1w = (const float*)d_in[10];
  const float* f1b = (const float*)d_in[11];
  const float* f2w = (const float*)d_in[12];
  const float* f2b = (const float*)d_in[13];
  const float* f3w = (const float*)d_in[14];
  const float* f3b = (const float*)d_in[15];
  float* out = (float*)d_out;

  float*  A  = (float*)d_ws;
  float*  C  = A + 4096 * 256;
  bf16_t* Wt = (bf16_t*)(C + 4096 * 256);
  float*  xg = (float*)((char*)Wt + 3 * 65536 * sizeof(bf16_t));

  rn_prep_kernel<<<256 + 48 + 64, 256, 0, stream>>>(
      x, qst, g1w, g1b, g2w, g3w, g4w, A, C, Wt, xg);
  rn_main_kernel<<<2048, 256, 0, stream>>>(A, C, Wt, g2b, g3b, g4b, xg);
  rn_f_kernel<<<64, 256, 0, stream>>>(xg, f1w, f1b, f2w, f2b, f3w, f3b, out);
}

// Round 3
// 314.531 us; speedup vs baseline: 1.1351x; 1.0961x over previous
//
#include <hip/hip_runtime.h>

typedef __bf16 bf16_t;
typedef __bf16 bf16x8 __attribute__((ext_vector_type(8)));
typedef __bf16 bf16x4 __attribute__((ext_vector_type(4)));
typedef float  f32x4  __attribute__((ext_vector_type(4)));

// ---------------------------------------------------------------------------
// Workspace layout (floats unless noted):
//   A  : [4096][256] f32   (xf @ W1[0:26])                       4 MB
//   C  : [4096][256] f32   (xf @ W1[26:52] + qst @ W1[52:180] + b1)  4 MB
//   Wt : 3 x [256][256] bf16 in MFMA A-fragment layout:
//        [mat][tile16(no>>4)][ks(k>>5)][lane(q*16+r)][e]  where
//        no = n-row, q=(k>>3)&3, r=no&15, e=k&7.  Per-(tile,ks) wave load
//        is one coalesced 1 KB transaction.                      384 KB
//   xg : [64][256] f32     (pair-summed g output)                64 KB
//
// h in LDS uses the matching B-fragment-linear layout:
//   h[chunk = mt*8+ks][lane = q*16+r][e]  <->  h[m = mt*16+r][k = ks*32+q*8+e]
// so ALL LDS reads/writes are lane-contiguous -> zero bank conflicts by
// construction (the old [row][col]+XOR layout measured a pegged 2^23
// SQ_LDS_BANK_CONFLICT and was the dominant cost).
// ---------------------------------------------------------------------------

// ---------------- prep: A, C, weight fragment-relayout, zero xg -------------
__global__ __launch_bounds__(256) void rn_prep_kernel(
    const float* __restrict__ x, const float* __restrict__ qst,
    const float* __restrict__ g1w, const float* __restrict__ g1b,
    const float* __restrict__ g2w, const float* __restrict__ g3w,
    const float* __restrict__ g4w,
    float* __restrict__ A, float* __restrict__ C,
    bf16_t* __restrict__ Wt, float* __restrict__ xg)
{
  __shared__ float T[64][65];   // transpose tile (only used by that branch)
  int blk = blockIdx.x;
  int n   = threadIdx.x;  // 0..255
  if (blk < 256) {
    // block = (b, jg): rows jg*16 .. jg*16+15 of batch b; thread = output col n
    int b  = blk >> 2;
    int jg = (blk & 3) * 16;
    float accQ = g1b[n];
    const float* qb = qst + b * 128;
    #pragma unroll 8
    for (int qi = 0; qi < 128; ++qi)
      accQ += qb[qi] * g1w[(52 + qi) * 256 + n];

    float w24 = g1w[24 * 256 + n], w25 = g1w[25 * 256 + n];
    float w50 = g1w[50 * 256 + n], w51 = g1w[51 * 256 + n];
    float accA[16], accC[16];
    #pragma unroll
    for (int t = 0; t < 16; ++t) {
      int j = jg + t;
      // faithful to (a/d - d/2)/(d/2.0) float arithmetic, d=8 (exact pow2 ops)
      float cx = ((float)j * 0.125f - 4.0f) * 0.25f;
      float cy = ((float)(j & 7) - 4.0f) * 0.25f;
      accA[t] = cx * w24 + cy * w25;
      accC[t] = accQ + cx * w50 + cy * w51;
    }
    for (int c = 0; c < 24; ++c) {
      float wa = g1w[c * 256 + n];
      float wc = g1w[(26 + c) * 256 + n];
      const float* xc = x + (b * 24 + c) * 64 + jg;
      #pragma unroll
      for (int t = 0; t < 16; ++t) {
        float xv = xc[t];   // uniform per thread -> scalar load
        accA[t] += xv * wa;
        accC[t] += xv * wc;
      }
    }
    #pragma unroll
    for (int t = 0; t < 16; ++t) {
      A[(b * 64 + jg + t) * 256 + n] = accA[t];
      C[(b * 64 + jg + t) * 256 + n] = accC[t];
    }
  } else if (blk < 256 + 48) {
    // LDS-tiled transpose: g2/g3/g4 [in(k)][out(no)] f32 -> bf16 fragment
    // layout: element (no,k) -> [(no>>4)*8 + (k>>5)][((k>>3)&3)*16 + (no&15)][k&7]
    int t   = blk - 256;
    int mat = t >> 4;                 // 0..2
    int tl  = t & 15;                 // 4x4 tiles of 64x64
    int kt  = (tl & 3) * 64;
    int nt_ = (tl >> 2) * 64;
    const float* W = (mat == 0) ? g2w : (mat == 1 ? g3w : g4w);
    int lane = n & 63, w = n >> 6;
    #pragma unroll
    for (int it = 0; it < 16; ++it) {
      int kl = w * 16 + it;
      T[kl][lane] = W[(kt + kl) * 256 + nt_ + lane];   // coalesced 256B/wave
    }
    __syncthreads();
    #pragma unroll
    for (int it = 0; it < 16; ++it) {
      int nl  = w * 16 + it;
      int no  = nt_ + nl;     // output-neuron index
      int k   = kt + lane;    // input index
      int tile = no >> 4, rr = no & 15;
      int ksI  = k >> 5,  qI = (k >> 3) & 3, e = k & 7;
      int idx  = ((tile * 8 + ksI) * 64 + qI * 16 + rr) * 8 + e;
      Wt[mat * 65536 + idx] = (bf16_t)T[lane][nl];
    }
  } else {
    int idx = (blk - (256 + 48)) * 256 + n;  // 64 blocks -> 16384
    xg[idx] = 0.f;
  }
}

// ---------------- main fused g-MLP (layers 2..4) + pair sum ----------------
// one block per (b, i-pair): M = 128 rows (2 i-values x 64 j), N = K = 256.
// Wave tiling: wave = (nh = wave>>1, mh = wave&1):
//   n-range 128 (nt=0..7), m-range 64 = buffer h_{mh} (mt=0..3).
// Per ks: 4 hf LDS reads + 8 wf global (L1-shared across blocks) -> 32 MFMA.
// vs the old 8 hf + 4 wf: LDS read count halves; wf extra reads are L1 hits
// since every block reads the same 16 KB W slice per ks-round, barrier-synced.
// All LDS accesses are lane-contiguous (fragment-linear layout): 0 conflicts.
// acc[8][4] = 128 AGPR + ~100 arch VGPR -> fits 256 budget at 2 blocks/CU.
__global__ __launch_bounds__(256, 2) void rn_main_kernel(
    const float* __restrict__ A, const float* __restrict__ C,
    const bf16_t* __restrict__ Wt,
    const float* __restrict__ g2b, const float* __restrict__ g3b,
    const float* __restrict__ g4b,
    float* __restrict__ xg)
{
  __shared__ bf16_t h0[16384];   // 32 KB: [chunk=mt*8+ks][lane][8]
  __shared__ bf16_t h1[16384];   // 32 KB

  int tid  = threadIdx.x;
  int bx0  = blockIdx.x;
  // bijective XCD swizzle (2048 % 8 == 0): 256 consecutive work-units per
  // XCD -> the 32 blocks sharing a batch b stay on one XCD's L2
  int bx   = (bx0 & 7) * 256 + (bx0 >> 3);
  int b    = bx >> 5;          // batch
  int ip   = bx & 31;          // i-pair: i = 2*ip, 2*ip+1
  int lane = tid & 63;
  int wave = tid >> 6;
  int r    = lane & 15;        // 16-dim index within MFMA tile
  int q    = lane >> 4;        // quad: k-run selector / D-row group

  // ---- build h rows into fragment-linear layout ----
  // wave w builds chunks (mt=w, ks=it): thread (q,r) -> m-row j = w*16+r,
  // k-run = it*32+q*8.  LDS writes are lane-contiguous 1 KB per instr.
  {
    const float* Ab = A + (size_t)b * 64 * 256;
    const float* Cr = C + ((size_t)b * 64 + ip * 2) * 256;
    int j = wave * 16 + r;
    #pragma unroll
    for (int it = 0; it < 8; ++it) {
      int k0 = it * 32 + q * 8;
      const float4 a0  = *(const float4*)(Ab + j * 256 + k0);
      const float4 a1  = *(const float4*)(Ab + j * 256 + k0 + 4);
      const float4 c00 = *(const float4*)(Cr + k0);
      const float4 c01 = *(const float4*)(Cr + k0 + 4);
      const float4 c10 = *(const float4*)(Cr + 256 + k0);
      const float4 c11 = *(const float4*)(Cr + 256 + k0 + 4);
      bf16x8 v0, v1;
      v0[0] = (bf16_t)fmaxf(a0.x + c00.x, 0.f);
      v0[1] = (bf16_t)fmaxf(a0.y + c00.y, 0.f);
      v0[2] = (bf16_t)fmaxf(a0.z + c00.z, 0.f);
      v0[3] = (bf16_t)fmaxf(a0.w + c00.w, 0.f);
      v0[4] = (bf16_t)fmaxf(a1.x + c01.x, 0.f);
      v0[5] = (bf16_t)fmaxf(a1.y + c01.y, 0.f);
      v0[6] = (bf16_t)fmaxf(a1.z + c01.z, 0.f);
      v0[7] = (bf16_t)fmaxf(a1.w + c01.w, 0.f);
      v1[0] = (bf16_t)fmaxf(a0.x + c10.x, 0.f);
      v1[1] = (bf16_t)fmaxf(a0.y + c10.y, 0.f);
      v1[2] = (bf16_t)fmaxf(a0.z + c10.z, 0.f);
      v1[3] = (bf16_t)fmaxf(a0.w + c10.w, 0.f);
      v1[4] = (bf16_t)fmaxf(a1.x + c11.x, 0.f);
      v1[5] = (bf16_t)fmaxf(a1.y + c11.y, 0.f);
      v1[6] = (bf16_t)fmaxf(a1.z + c11.z, 0.f);
      v1[7] = (bf16_t)fmaxf(a1.w + c11.w, 0.f);
      int off = ((wave * 8 + it) * 64 + lane) * 8;
      *(bf16x8*)&h0[off] = v0;
      *(bf16x8*)&h1[off] = v1;
    }
  }

  int nh = wave >> 1;          // n-half: rows nh*128 .. +127 of W
  int mh = wave & 1;           // m-half: which h buffer this wave owns
  bf16_t* hb = mh ? h1 : h0;

  for (int L = 0; L < 3; ++L) {
    __syncthreads();           // h (build or previous epilogue) visible
    const bf16_t* Wl   = Wt + L * 65536 + nh * 32768;
    const float*  bias = (L == 0) ? g2b : (L == 1) ? g3b : g4b;

    f32x4 acc[8][4];           // [nt][mt]
    #pragma unroll
    for (int nt = 0; nt < 8; ++nt)
      #pragma unroll
      for (int mt = 0; mt < 4; ++mt)
        #pragma unroll
        for (int e = 0; e < 4; ++e) acc[nt][mt][e] = 0.f;

    #pragma unroll
    for (int ks = 0; ks < 8; ++ks) {
      bf16x8 hf[4], wf[8];
      #pragma unroll
      for (int mt = 0; mt < 4; ++mt)
        hf[mt] = *(const bf16x8*)&hb[((mt * 8 + ks) * 64 + lane) * 8];
      #pragma unroll
      for (int nt = 0; nt < 8; ++nt)
        wf[nt] = *(const bf16x8*)&Wl[((nt * 8 + ks) * 64 + lane) * 8];
      #pragma unroll
      for (int nt = 0; nt < 8; ++nt)
        #pragma unroll
        for (int mt = 0; mt < 4; ++mt)
          acc[nt][mt] = __builtin_amdgcn_mfma_f32_16x16x32_bf16(
              wf[nt], hf[mt], acc[nt][mt], 0, 0, 0);
    }

    __syncthreads();           // all reads of h done -> safe to overwrite

    if (L < 2) {
      // D value (nt,mt,e): n = nh*128+nt*16+q*4+e (next layer's k),
      // m = mt*16+r.  Write into fragment-linear slot of hb.
      #pragma unroll
      for (int nt = 0; nt < 8; ++nt) {
        int k0  = nh * 128 + nt * 16 + q * 4;
        float4 bv = *(const float4*)&bias[k0];
        int ks_ = k0 >> 5, rem = k0 & 31;
        int qp  = rem >> 3, e0 = rem & 7;     // e0 in {0,4}
        #pragma unroll
        for (int mt = 0; mt < 4; ++mt) {
          bf16x4 v;
          v[0] = (bf16_t)fmaxf(acc[nt][mt][0] + bv.x, 0.f);
          v[1] = (bf16_t)fmaxf(acc[nt][mt][1] + bv.y, 0.f);
          v[2] = (bf16_t)fmaxf(acc[nt][mt][2] + bv.z, 0.f);
          v[3] = (bf16_t)fmaxf(acc[nt][mt][3] + bv.w, 0.f);
          int off = ((mt * 8 + ks_) * 64 + qp * 16 + r) * 8 + e0;
          *(bf16x4*)&hb[off] = v;
        }
      }
    } else {
      // last layer: bias+relu fp32, sum over this wave's 64 m-rows
      // (mt in-register, then the 16 r-lanes), atomic to xg.
      #pragma unroll
      for (int nt = 0; nt < 8; ++nt) {
        int k0 = nh * 128 + nt * 16 + q * 4;
        float4 bv = *(const float4*)&bias[k0];
        float p0 = 0.f, p1 = 0.f, p2 = 0.f, p3 = 0.f;
        #pragma unroll
        for (int mt = 0; mt < 4; ++mt) {
          p0 += fmaxf(acc[nt][mt][0] + bv.x, 0.f);
          p1 += fmaxf(acc[nt][mt][1] + bv.y, 0.f);
          p2 += fmaxf(acc[nt][mt][2] + bv.z, 0.f);
          p3 += fmaxf(acc[nt][mt][3] + bv.w, 0.f);
        }
        #pragma unroll
        for (int d = 1; d < 16; d <<= 1) {
          p0 += __shfl_xor(p0, d, 64);
          p1 += __shfl_xor(p1, d, 64);
          p2 += __shfl_xor(p2, d, 64);
          p3 += __shfl_xor(p3, d, 64);
        }
        if (r == 0) {
          int nn = b * 256 + k0;
          atomicAdd(&xg[nn + 0], p0);
          atomicAdd(&xg[nn + 1], p1);
          atomicAdd(&xg[nn + 2], p2);
          atomicAdd(&xg[nn + 3], p3);
        }
      }
    }
  }
}

// ---------------- f-MLP + log_softmax (tiny, fp32) ----------------
__global__ __launch_bounds__(256) void rn_f_kernel(
    const float* __restrict__ xg,
    const float* __restrict__ f1w, const float* __restrict__ f1b,
    const float* __restrict__ f2w, const float* __restrict__ f2b,
    const float* __restrict__ f3w, const float* __restrict__ f3b,
    float* __restrict__ out)
{
  __shared__ float xs[256], t1[256], t2[256], lg[28], lse[1];
  int b = blockIdx.x, tid = threadIdx.x;
  xs[tid] = xg[b * 256 + tid];
  __syncthreads();
  float acc = f1b[tid];
  for (int k = 0; k < 256; ++k) acc += xs[k] * f1w[k * 256 + tid];
  t1[tid] = fmaxf(acc, 0.f);
  __syncthreads();
  acc = f2b[tid];
  for (int k = 0; k < 256; ++k) acc += t1[k] * f2w[k * 256 + tid];
  t2[tid] = fmaxf(acc, 0.f);
  __syncthreads();
  if (tid < 28) {
    float a2 = f3b[tid];
    for (int k = 0; k < 256; ++k) a2 += t2[k] * f3w[k * 28 + tid];
    lg[tid] = a2;
  }
  __syncthreads();
  if (tid == 0) {
    float m = lg[0];
    for (int j = 1; j < 28; ++j) m = fmaxf(m, lg[j]);
    float se = 0.f;
    for (int j = 0; j < 28; ++j) se += expf(lg[j] - m);
    lse[0] = m + logf(se);
  }
  __syncthreads();
  if (tid < 28) out[b * 28 + tid] = lg[tid] - lse[0];
}

// ---------------------------------------------------------------------------
extern "C" void kernel_launch(void* const* d_in, const int* in_sizes, int n_in,
                              void* d_out, int out_size, void* d_ws, size_t ws_size,
                              hipStream_t stream) {
  (void)in_sizes; (void)n_in; (void)out_size; (void)ws_size;
  const float* x   = (const float*)d_in[0];
  const float* qst = (const float*)d_in[1];
  const float* g1w = (const float*)d_in[2];
  const float* g1b = (const float*)d_in[3];
  const float* g2w = (const float*)d_in[4];
  const float* g2b = (const float*)d_in[5];
  const float* g3w = (const float*)d_in[6];
  const float* g3b = (const float*)d_in[7];
  const float* g4w = (const float*)d_in[8];
  const float* g4b = (const float*)d_in[9];
  const float* f1w = (const float*)d_in[10];
  const float* f1b = (const float*)d_in[11];
  const float* f2w = (const float*)d_in[12];
  const float* f2b = (const float*)d_in[13];
  const float* f3w = (const float*)d_in[14];
  const float* f3b = (const float*)d_in[15];
  float* out = (float*)d_out;

  float*  A  = (float*)d_ws;
  float*  C  = A + 4096 * 256;
  bf16_t* Wt = (bf16_t*)(C + 4096 * 256);
  float*  xg = (float*)((char*)Wt + 3 * 65536 * sizeof(bf16_t));

  rn_prep_kernel<<<256 + 48 + 64, 256, 0, stream>>>(
      x, qst, g1w, g1b, g2w, g3w, g4w, A, C, Wt, xg);
  rn_main_kernel<<<2048, 256, 0, stream>>>(A, C, Wt, g2b, g3b, g4b, xg);
  rn_f_kernel<<<64, 256, 0, stream>>>(xg, f1w, f1b, f2w, f2b, f3w, f3b, out);
}

// Round 4
// 246.225 us; speedup vs baseline: 1.4500x; 1.2774x over previous
//
#include <hip/hip_runtime.h>

typedef __bf16 bf16_t;
typedef __bf16 bf16x8 __attribute__((ext_vector_type(8)));
typedef __bf16 bf16x4 __attribute__((ext_vector_type(4)));
typedef float  f32x4  __attribute__((ext_vector_type(4)));

// ---------------------------------------------------------------------------
// Workspace layout (floats unless noted):
//   A  : [4096][256] f32   (xf @ W1[0:26])                       4 MB
//   C  : [4096][256] f32   (xf @ W1[26:52] + qst @ W1[52:180] + b1)  4 MB
//   Wt : 3 x [256][256] bf16 in MFMA A-fragment layout:
//        [mat][tile16(no>>4)][ks(k>>5)][lane(q*16+r)][e]  where
//        no = n-row, q=(k>>3)&3, r=no&15, e=k&7.  Per-(tile,ks) wave load
//        is one coalesced 1 KB transaction.                      384 KB
//   xg : [64][256] f32     (pair-summed g output)                64 KB
//
// h in LDS uses the matching B-fragment-linear layout:
//   h[chunk = mt*8+ks][lane = q*16+r][e]  <->  h[m = mt*16+r][k = ks*32+q*8+e]
// so ALL LDS reads/writes are lane-contiguous -> zero bank conflicts by
// construction.
//
// Round-4 operand split (post-mortem of r3): wave owns n=64 (4 wf global,
// one 1KB transaction each) x m=128 (8 hf from LDS).  r3's 8-wf-global
// variant left MfmaUtil at 20% (= the bare 50us MFMA floor spread over
// 210us): per-ks global-load latency bursts at 2 waves/SIMD were the
// serializer.  Halving the global fragment count and feeding the other
// half from low-latency conflict-free LDS is the direct fix.
// ---------------------------------------------------------------------------

// ---------------- prep: A, C, weight fragment-relayout, zero xg -------------
__global__ __launch_bounds__(256) void rn_prep_kernel(
    const float* __restrict__ x, const float* __restrict__ qst,
    const float* __restrict__ g1w, const float* __restrict__ g1b,
    const float* __restrict__ g2w, const float* __restrict__ g3w,
    const float* __restrict__ g4w,
    float* __restrict__ A, float* __restrict__ C,
    bf16_t* __restrict__ Wt, float* __restrict__ xg)
{
  __shared__ float T[64][65];   // transpose tile (only used by that branch)
  int blk = blockIdx.x;
  int n   = threadIdx.x;  // 0..255
  if (blk < 256) {
    // block = (b, jg): rows jg*16 .. jg*16+15 of batch b; thread = output col n
    int b  = blk >> 2;
    int jg = (blk & 3) * 16;
    float accQ = g1b[n];
    const float* qb = qst + b * 128;
    #pragma unroll 8
    for (int qi = 0; qi < 128; ++qi)
      accQ += qb[qi] * g1w[(52 + qi) * 256 + n];

    float w24 = g1w[24 * 256 + n], w25 = g1w[25 * 256 + n];
    float w50 = g1w[50 * 256 + n], w51 = g1w[51 * 256 + n];
    float accA[16], accC[16];
    #pragma unroll
    for (int t = 0; t < 16; ++t) {
      int j = jg + t;
      // faithful to (a/d - d/2)/(d/2.0) float arithmetic, d=8 (exact pow2 ops)
      float cx = ((float)j * 0.125f - 4.0f) * 0.25f;
      float cy = ((float)(j & 7) - 4.0f) * 0.25f;
      accA[t] = cx * w24 + cy * w25;
      accC[t] = accQ + cx * w50 + cy * w51;
    }
    for (int c = 0; c < 24; ++c) {
      float wa = g1w[c * 256 + n];
      float wc = g1w[(26 + c) * 256 + n];
      const float* xc = x + (b * 24 + c) * 64 + jg;
      #pragma unroll
      for (int t = 0; t < 16; ++t) {
        float xv = xc[t];   // uniform per thread -> scalar load
        accA[t] += xv * wa;
        accC[t] += xv * wc;
      }
    }
    #pragma unroll
    for (int t = 0; t < 16; ++t) {
      A[(b * 64 + jg + t) * 256 + n] = accA[t];
      C[(b * 64 + jg + t) * 256 + n] = accC[t];
    }
  } else if (blk < 256 + 48) {
    // LDS-tiled transpose: g2/g3/g4 [in(k)][out(no)] f32 -> bf16 fragment
    // layout: element (no,k) -> [(no>>4)*8 + (k>>5)][((k>>3)&3)*16 + (no&15)][k&7]
    int t   = blk - 256;
    int mat = t >> 4;                 // 0..2
    int tl  = t & 15;                 // 4x4 tiles of 64x64
    int kt  = (tl & 3) * 64;
    int nt_ = (tl >> 2) * 64;
    const float* W = (mat == 0) ? g2w : (mat == 1 ? g3w : g4w);
    int lane = n & 63, w = n >> 6;
    #pragma unroll
    for (int it = 0; it < 16; ++it) {
      int kl = w * 16 + it;
      T[kl][lane] = W[(kt + kl) * 256 + nt_ + lane];   // coalesced 256B/wave
    }
    __syncthreads();
    #pragma unroll
    for (int it = 0; it < 16; ++it) {
      int nl  = w * 16 + it;
      int no  = nt_ + nl;     // output-neuron index
      int k   = kt + lane;    // input index
      int tile = no >> 4, rr = no & 15;
      int ksI  = k >> 5,  qI = (k >> 3) & 3, e = k & 7;
      int idx  = ((tile * 8 + ksI) * 64 + qI * 16 + rr) * 8 + e;
      Wt[mat * 65536 + idx] = (bf16_t)T[lane][nl];
    }
  } else {
    int idx = (blk - (256 + 48)) * 256 + n;  // 64 blocks -> 16384
    xg[idx] = 0.f;
  }
}

// ---------------- main fused g-MLP (layers 2..4) + pair sum ----------------
// one block per (b, i-pair): M = 128 rows (2 i-values x 64 j), N = K = 256.
// Wave tiling: wave owns n-rows [wave*64, wave*64+64) (nt=0..3) and ALL
// 128 m-rows (mt=0..7: h0 for mt<4, h1 for mt>=4).
// Per ks: 4 wf global (1 KB contiguous each, L1-shared across blocks)
//       + 8 hf LDS (lane-contiguous, conflict-free) -> 32 MFMA.
// acc[4][8] = 128 AGPR + ~100 arch VGPR -> fits 256 budget at 2 blocks/CU.
__global__ __launch_bounds__(256, 2) void rn_main_kernel(
    const float* __restrict__ A, const float* __restrict__ C,
    const bf16_t* __restrict__ Wt,
    const float* __restrict__ g2b, const float* __restrict__ g3b,
    const float* __restrict__ g4b,
    float* __restrict__ xg)
{
  __shared__ bf16_t h0[16384];   // 32 KB: [chunk=mt*8+ks][lane][8]
  __shared__ bf16_t h1[16384];   // 32 KB

  int tid  = threadIdx.x;
  int bx0  = blockIdx.x;
  // bijective XCD swizzle (2048 % 8 == 0): 256 consecutive work-units per
  // XCD -> the 32 blocks sharing a batch b stay on one XCD's L2
  int bx   = (bx0 & 7) * 256 + (bx0 >> 3);
  int b    = bx >> 5;          // batch
  int ip   = bx & 31;          // i-pair: i = 2*ip, 2*ip+1
  int lane = tid & 63;
  int wave = tid >> 6;
  int r    = lane & 15;        // 16-dim index within MFMA tile
  int q    = lane >> 4;        // quad: k-run selector / D-row group

  // ---- build h rows into fragment-linear layout ----
  // wave w builds chunks (mt=w, ks=it): thread (q,r) -> m-row j = w*16+r,
  // k-run = it*32+q*8.  LDS writes are lane-contiguous 1 KB per instr.
  {
    const float* Ab = A + (size_t)b * 64 * 256;
    const float* Cr = C + ((size_t)b * 64 + ip * 2) * 256;
    int j = wave * 16 + r;
    #pragma unroll
    for (int it = 0; it < 8; ++it) {
      int k0 = it * 32 + q * 8;
      const float4 a0  = *(const float4*)(Ab + j * 256 + k0);
      const float4 a1  = *(const float4*)(Ab + j * 256 + k0 + 4);
      const float4 c00 = *(const float4*)(Cr + k0);
      const float4 c01 = *(const float4*)(Cr + k0 + 4);
      const float4 c10 = *(const float4*)(Cr + 256 + k0);
      const float4 c11 = *(const float4*)(Cr + 256 + k0 + 4);
      bf16x8 v0, v1;
      v0[0] = (bf16_t)fmaxf(a0.x + c00.x, 0.f);
      v0[1] = (bf16_t)fmaxf(a0.y + c00.y, 0.f);
      v0[2] = (bf16_t)fmaxf(a0.z + c00.z, 0.f);
      v0[3] = (bf16_t)fmaxf(a0.w + c00.w, 0.f);
      v0[4] = (bf16_t)fmaxf(a1.x + c01.x, 0.f);
      v0[5] = (bf16_t)fmaxf(a1.y + c01.y, 0.f);
      v0[6] = (bf16_t)fmaxf(a1.z + c01.z, 0.f);
      v0[7] = (bf16_t)fmaxf(a1.w + c01.w, 0.f);
      v1[0] = (bf16_t)fmaxf(a0.x + c10.x, 0.f);
      v1[1] = (bf16_t)fmaxf(a0.y + c10.y, 0.f);
      v1[2] = (bf16_t)fmaxf(a0.z + c10.z, 0.f);
      v1[3] = (bf16_t)fmaxf(a0.w + c10.w, 0.f);
      v1[4] = (bf16_t)fmaxf(a1.x + c11.x, 0.f);
      v1[5] = (bf16_t)fmaxf(a1.y + c11.y, 0.f);
      v1[6] = (bf16_t)fmaxf(a1.z + c11.z, 0.f);
      v1[7] = (bf16_t)fmaxf(a1.w + c11.w, 0.f);
      int off = ((wave * 8 + it) * 64 + lane) * 8;
      *(bf16x8*)&h0[off] = v0;
      *(bf16x8*)&h1[off] = v1;
    }
  }

  for (int L = 0; L < 3; ++L) {
    __syncthreads();           // h (build or previous epilogue) visible
    // this wave's 4 W tiles: tile = wave*4 + nt  -> base offset wave*16384
    const bf16_t* Wl   = Wt + L * 65536 + wave * 16384;
    const float*  bias = (L == 0) ? g2b : (L == 1) ? g3b : g4b;

    f32x4 acc[4][8];           // [nt][mt]
    #pragma unroll
    for (int nt = 0; nt < 4; ++nt)
      #pragma unroll
      for (int mt = 0; mt < 8; ++mt)
        #pragma unroll
        for (int e = 0; e < 4; ++e) acc[nt][mt][e] = 0.f;

    #pragma unroll
    for (int ks = 0; ks < 8; ++ks) {
      bf16x8 wf[4], hf[8];
      #pragma unroll
      for (int nt = 0; nt < 4; ++nt)
        wf[nt] = *(const bf16x8*)&Wl[((nt * 8 + ks) * 64 + lane) * 8];
      #pragma unroll
      for (int mt = 0; mt < 8; ++mt) {
        const bf16_t* hb = (mt < 4) ? h0 : h1;
        hf[mt] = *(const bf16x8*)&hb[(((mt & 3) * 8 + ks) * 64 + lane) * 8];
      }
      #pragma unroll
      for (int nt = 0; nt < 4; ++nt)
        #pragma unroll
        for (int mt = 0; mt < 8; ++mt)
          acc[nt][mt] = __builtin_amdgcn_mfma_f32_16x16x32_bf16(
              wf[nt], hf[mt], acc[nt][mt], 0, 0, 0);
    }

    __syncthreads();           // all reads of h done -> safe to overwrite

    if (L < 2) {
      // D value (nt,mt,e): n = wave*64+nt*16+q*4+e (next layer's k),
      // m = mt*16+r (mt<4 -> h0, else h1).  Fragment-linear write-back.
      #pragma unroll
      for (int nt = 0; nt < 4; ++nt) {
        int k0  = wave * 64 + nt * 16 + q * 4;
        float4 bv = *(const float4*)&bias[k0];
        int ks_ = k0 >> 5, rem = k0 & 31;
        int qp  = rem >> 3, e0 = rem & 7;     // e0 in {0,4}
        #pragma unroll
        for (int mt = 0; mt < 8; ++mt) {
          bf16_t* hb = (mt < 4) ? h0 : h1;
          bf16x4 v;
          v[0] = (bf16_t)fmaxf(acc[nt][mt][0] + bv.x, 0.f);
          v[1] = (bf16_t)fmaxf(acc[nt][mt][1] + bv.y, 0.f);
          v[2] = (bf16_t)fmaxf(acc[nt][mt][2] + bv.z, 0.f);
          v[3] = (bf16_t)fmaxf(acc[nt][mt][3] + bv.w, 0.f);
          int off = (((mt & 3) * 8 + ks_) * 64 + qp * 16 + r) * 8 + e0;
          *(bf16x4*)&hb[off] = v;
        }
      }
    } else {
      // last layer: bias+relu fp32, sum over all 128 m-rows
      // (mt in-register, then the 16 r-lanes), atomic to xg.
      #pragma unroll
      for (int nt = 0; nt < 4; ++nt) {
        int k0 = wave * 64 + nt * 16 + q * 4;
        float4 bv = *(const float4*)&bias[k0];
        float p0 = 0.f, p1 = 0.f, p2 = 0.f, p3 = 0.f;
        #pragma unroll
        for (int mt = 0; mt < 8; ++mt) {
          p0 += fmaxf(acc[nt][mt][0] + bv.x, 0.f);
          p1 += fmaxf(acc[nt][mt][1] + bv.y, 0.f);
          p2 += fmaxf(acc[nt][mt][2] + bv.z, 0.f);
          p3 += fmaxf(acc[nt][mt][3] + bv.w, 0.f);
        }
        #pragma unroll
        for (int d = 1; d < 16; d <<= 1) {
          p0 += __shfl_xor(p0, d, 64);
          p1 += __shfl_xor(p1, d, 64);
          p2 += __shfl_xor(p2, d, 64);
          p3 += __shfl_xor(p3, d, 64);
        }
        if (r == 0) {
          int nn = b * 256 + k0;
          atomicAdd(&xg[nn + 0], p0);
          atomicAdd(&xg[nn + 1], p1);
          atomicAdd(&xg[nn + 2], p2);
          atomicAdd(&xg[nn + 3], p3);
        }
      }
    }
  }
}

// ---------------- f-MLP + log_softmax (tiny, fp32) ----------------
__global__ __launch_bounds__(256) void rn_f_kernel(
    const float* __restrict__ xg,
    const float* __restrict__ f1w, const float* __restrict__ f1b,
    const float* __restrict__ f2w, const float* __restrict__ f2b,
    const float* __restrict__ f3w, const float* __restrict__ f3b,
    float* __restrict__ out)
{
  __shared__ float xs[256], t1[256], t2[256], lg[28], lse[1];
  int b = blockIdx.x, tid = threadIdx.x;
  xs[tid] = xg[b * 256 + tid];
  __syncthreads();
  float acc = f1b[tid];
  for (int k = 0; k < 256; ++k) acc += xs[k] * f1w[k * 256 + tid];
  t1[tid] = fmaxf(acc, 0.f);
  __syncthreads();
  acc = f2b[tid];
  for (int k = 0; k < 256; ++k) acc += t1[k] * f2w[k * 256 + tid];
  t2[tid] = fmaxf(acc, 0.f);
  __syncthreads();
  if (tid < 28) {
    float a2 = f3b[tid];
    for (int k = 0; k < 256; ++k) a2 += t2[k] * f3w[k * 28 + tid];
    lg[tid] = a2;
  }
  __syncthreads();
  if (tid == 0) {
    float m = lg[0];
    for (int j = 1; j < 28; ++j) m = fmaxf(m, lg[j]);
    float se = 0.f;
    for (int j = 0; j < 28; ++j) se += expf(lg[j] - m);
    lse[0] = m + logf(se);
  }
  __syncthreads();
  if (tid < 28) out[b * 28 + tid] = lg[tid] - lse[0];
}

// ---------------------------------------------------------------------------
extern "C" void kernel_launch(void* const* d_in, const int* in_sizes, int n_in,
                              void* d_out, int out_size, void* d_ws, size_t ws_size,
                              hipStream_t stream) {
  (void)in_sizes; (void)n_in; (void)out_size; (void)ws_size;
  const float* x   = (const float*)d_in[0];
  const float* qst = (const float*)d_in[1];
  const float* g1w = (const float*)d_in[2];
  const float* g1b = (const float*)d_in[3];
  const float* g2w = (const float*)d_in[4];
  const float* g2b = (const float*)d_in[5];
  const float* g3w = (const float*)d_in[6];
  const float* g3b = (const float*)d_in[7];
  const float* g4w = (const float*)d_in[8];
  const float* g4b = (const float*)d_in[9];
  const float* f1w = (const float*)d_in[10];
  const float* f1b = (const float*)d_in[11];
  const float* f2w = (const float*)d_in[12];
  const float* f2b = (const float*)d_in[13];
  const float* f3w = (const float*)d_in[14];
  const float* f3b = (const float*)d_in[15];
  float* out = (float*)d_out;

  float*  A  = (float*)d_ws;
  float*  C  = A + 4096 * 256;
  bf16_t* Wt = (bf16_t*)(C + 4096 * 256);
  float*  xg = (float*)((char*)Wt + 3 * 65536 * sizeof(bf16_t));

  rn_prep_kernel<<<256 + 48 + 64, 256, 0, stream>>>(
      x, qst, g1w, g1b, g2w, g3w, g4w, A, C, Wt, xg);
  rn_main_kernel<<<2048, 256, 0, stream>>>(A, C, Wt, g2b, g3b, g4b, xg);
  rn_f_kernel<<<64, 256, 0, stream>>>(xg, f1w, f1b, f2w, f2b, f3w, f3b, out);
}